// Round 8
// baseline (213.612 us; speedup 1.0000x reference)
//
#include <hip/hip_runtime.h>
#include <hip/hip_bf16.h>
#include <stdint.h>

// B=4, S=2048, HDIM=1024, H=16, D=64, L=128, NB=16
// GEMMs: M = B*S = 8192, N = H*D = 1024, K = HDIM = 1024
constexpr int GM = 8192;
constexpr int GK = 1024;
constexpr int GN = 1024;
constexpr size_t NACT = (size_t)GM * GN;      // 8388608 elements
constexpr int CHUNK = 32;                      // scan chunk length
constexpr int NCHUNK = 64;                     // 64*32 = 2048 = S
constexpr int NCH = 4096;                      // B*H*D channels
constexpr int NT = GK / 64;                    // 16 K-tiles of 64

#define DEVINL __device__ __forceinline__

typedef __attribute__((ext_vector_type(8))) short bf16x8;
typedef __attribute__((ext_vector_type(4))) float f32x4;

DEVINL float sigmoidf_(float x) { return 1.0f / (1.0f + __expf(-x)); }

DEVINL unsigned short f2bf(float x) {
  unsigned int u = __builtin_bit_cast(unsigned int, x);
  unsigned int rnd = 0x7fffu + ((u >> 16) & 1u);
  return (unsigned short)((u + rnd) >> 16);
}
DEVINL float bf2f(unsigned short u) {
  unsigned int x = ((unsigned int)u) << 16;
  return __builtin_bit_cast(float, x);
}

DEVINL void gload16(const void* g, void* l) {
  __builtin_amdgcn_global_load_lds(
      (const __attribute__((address_space(1))) unsigned int*)g,
      (__attribute__((address_space(3))) unsigned int*)l, 16, 0, 0);
}

#define SB() __builtin_amdgcn_sched_barrier(0)

// ---------------- prep: cvt 4 activations + transpose 5 weights, ONE dispatch ----------------
struct PrepArgs {
  const float* csrc[4];
  unsigned short* cdst[4];
  const float* tsrc[5];
  unsigned short* tdst[5];
};

__global__ __launch_bounds__(256) void prep_kernel(PrepArgs p) {
  const int bx = blockIdx.x;
  if (bx < 4096) {
    // cvt part: 1024 blocks per array, 8 float4 per thread
    const float* s = p.csrc[bx >> 10];
    unsigned short* d = p.cdst[bx >> 10];
    int i = (bx & 1023) * 256 + threadIdx.x;
    const int stride = 1024 * 256;
#pragma unroll
    for (int it = 0; it < 8; ++it, i += stride) {
      float4 v = ((const float4*)s)[i];
      ushort4 o;
      o.x = f2bf(v.x); o.y = f2bf(v.y); o.z = f2bf(v.z); o.w = f2bf(v.w);
      ((ushort4*)d)[i] = o;
    }
  } else {
    // transpose part: 1024 blocks per weight (32x32 tiles over 1024^2)
    const int t = bx - 4096;
    const float* __restrict__ W = p.tsrc[t >> 10];
    unsigned short* __restrict__ Wt = p.tdst[t >> 10];
    const int rem = t & 1023;
    const int n0 = (rem & 31) * 32, k0 = (rem >> 5) * 32;
    __shared__ float tile[32][33];
    int tx = threadIdx.x & 31, ty = threadIdx.x >> 5;  // 32x8
#pragma unroll
    for (int i = 0; i < 32; i += 8)
      tile[ty + i][tx] = W[(size_t)(k0 + ty + i) * GN + n0 + tx];
    __syncthreads();
#pragma unroll
    for (int i = 0; i < 32; i += 8)
      Wt[(size_t)(n0 + ty + i) * GK + k0 + tx] = f2bf(tile[tx][ty + i]);
  }
}

// =====================================================================
// 256x256 tile, BK=64, 8 waves (2M x 4N) -- round-3 schedule (best: 86.4us).
//  P1: stage A(t+1); vmcnt(4); barrier; read q1; MFMA (mlo,nlo)
//  P2: read bF-hi; stage B(t+1); barrier; lgkm0; MFMA (mlo,nhi)
//  P3: read aF-hi; barrier; lgkm0; MFMA (mhi,nhi)
//  P4: MFMA (mhi,nlo) -- no loads/barrier; overlaps next P1 stage
// LDS 128 KiB: 2 dbuf x (A 32K + B 32K), linear dest + inverse-XOR-swizzled
// global source; reads apply the same XOR involution: cb ^= (row&7)<<4.
// =====================================================================
DEVINL void gemm256_core(const unsigned short* __restrict__ A,
                         const unsigned short* __restrict__ W,
                         char* lds, int tid, int wave, int lane,
                         int bm, int bn, f32x4 (&acc)[8][4]) {
  const int Ah = wave >> 2;
  const int wn = (wave & 3) * 64;
  const int lrow = lane & 15;
  const int lgrp = lane >> 4;

  const char* gsrc[8];
  char* ldst[8];
  {
    const char* Ag = (const char*)A;
    const char* Wg = (const char*)W;
#pragma unroll
    for (int hh = 0; hh < 4; ++hh)
#pragma unroll
      for (int j = 0; j < 2; ++j) {
        const int lbyte = j * 8192 + tid * 16;
        const int row = lbyte >> 7;
        const int gcb = (lbyte & 127) ^ ((row & 7) << 4);
        const int i = hh * 2 + j;
        gsrc[i] = (hh < 2)
            ? Ag + (size_t)(bm * 256 + hh * 128 + row) * 2048 + gcb
            : Wg + (size_t)(bn * 256 + (hh - 2) * 128 + row) * 2048 + gcb;
        ldst[i] = lds + (hh >= 2 ? 32768 : 0) + (hh & 1) * 16384 + j * 8192 +
                  wave * 1024;
      }
  }

#pragma unroll
  for (int i = 0; i < 8; ++i) gload16(gsrc[i], ldst[i]);

  bf16x8 aF[4][2], bF[4][2];

  for (int t = 0; t < NT; ++t) {
    const int cur = t & 1;
    const int obuf = (cur ^ 1) * 65536;
    const char* Abase = lds + cur * 65536 + Ah * 16384;
    const char* Bbase = lds + cur * 65536 + 32768;
    const int nk = (t + 1 < NT) ? (t + 1) : (NT - 1);
    const size_t koff = (size_t)nk * 128;

    // ---- P1 ----
#pragma unroll
    for (int i = 0; i < 4; ++i) gload16(gsrc[i] + koff, ldst[i] + obuf);
    asm volatile("s_waitcnt vmcnt(4)" ::: "memory");
    __builtin_amdgcn_s_barrier();
    SB();
#pragma unroll
    for (int m = 0; m < 4; ++m)
#pragma unroll
      for (int ks = 0; ks < 2; ++ks) {
        const int r = m * 16 + lrow;
        const int cb = ks * 64 + lgrp * 16;
        aF[m][ks] = *(const bf16x8*)(Abase + r * 128 + (cb ^ ((r & 7) << 4)));
      }
#pragma unroll
    for (int n = 0; n < 2; ++n)
#pragma unroll
      for (int ks = 0; ks < 2; ++ks) {
        const int nr = wn + n * 16 + lrow;
        const int cb = ks * 64 + lgrp * 16;
        bF[n][ks] = *(const bf16x8*)(Bbase + nr * 128 + (cb ^ ((nr & 7) << 4)));
      }
    __builtin_amdgcn_s_setprio(1);
#pragma unroll
    for (int m = 0; m < 4; ++m)
#pragma unroll
      for (int n = 0; n < 2; ++n)
#pragma unroll
        for (int ks = 0; ks < 2; ++ks)
          acc[m][n] = __builtin_amdgcn_mfma_f32_16x16x32_bf16(aF[m][ks], bF[n][ks],
                                                              acc[m][n], 0, 0, 0);
    __builtin_amdgcn_s_setprio(0);

    // ---- P2 ----
#pragma unroll
    for (int n = 2; n < 4; ++n)
#pragma unroll
      for (int ks = 0; ks < 2; ++ks) {
        const int nr = wn + n * 16 + lrow;
        const int cb = ks * 64 + lgrp * 16;
        bF[n][ks] = *(const bf16x8*)(Bbase + nr * 128 + (cb ^ ((nr & 7) << 4)));
      }
#pragma unroll
    for (int i = 4; i < 8; ++i) gload16(gsrc[i] + koff, ldst[i] + obuf);
    __builtin_amdgcn_s_barrier();
    asm volatile("s_waitcnt lgkmcnt(0)" ::: "memory");
    SB();
    __builtin_amdgcn_s_setprio(1);
#pragma unroll
    for (int m = 0; m < 4; ++m)
#pragma unroll
      for (int n = 2; n < 4; ++n)
#pragma unroll
        for (int ks = 0; ks < 2; ++ks)
          acc[m][n] = __builtin_amdgcn_mfma_f32_16x16x32_bf16(aF[m][ks], bF[n][ks],
                                                              acc[m][n], 0, 0, 0);
    __builtin_amdgcn_s_setprio(0);

    // ---- P3 ----
#pragma unroll
    for (int m = 0; m < 4; ++m)
#pragma unroll
      for (int ks = 0; ks < 2; ++ks) {
        const int r = (m + 4) * 16 + lrow;
        const int cb = ks * 64 + lgrp * 16;
        aF[m][ks] = *(const bf16x8*)(Abase + r * 128 + (cb ^ ((r & 7) << 4)));
      }
    __builtin_amdgcn_s_barrier();
    asm volatile("s_waitcnt lgkmcnt(0)" ::: "memory");
    SB();
    __builtin_amdgcn_s_setprio(1);
#pragma unroll
    for (int m = 0; m < 4; ++m)
#pragma unroll
      for (int n = 2; n < 4; ++n)
#pragma unroll
        for (int ks = 0; ks < 2; ++ks)
          acc[m + 4][n] = __builtin_amdgcn_mfma_f32_16x16x32_bf16(aF[m][ks], bF[n][ks],
                                                                  acc[m + 4][n], 0, 0, 0);
    __builtin_amdgcn_s_setprio(0);

    // ---- P4 ----
    __builtin_amdgcn_s_setprio(1);
#pragma unroll
    for (int m = 0; m < 4; ++m)
#pragma unroll
      for (int n = 0; n < 2; ++n)
#pragma unroll
        for (int ks = 0; ks < 2; ++ks)
          acc[m + 4][n] = __builtin_amdgcn_mfma_f32_16x16x32_bf16(aF[m][ks], bF[n][ks],
                                                                  acc[m + 4][n], 0, 0, 0);
    __builtin_amdgcn_s_setprio(0);
  }
}

// ---------------- batched gate GEMM: gz = {f->sig(+1), o->sig, i->sig, z->tanh} ----------------
struct GateArgs {
  const unsigned short* A[4];
  const unsigned short* W[4];
  const float* bias[4];
  unsigned short* out[4];
};

__global__ __launch_bounds__(512, 2) void gemm_gates8(GateArgs ga) {
  extern __shared__ char lds[];
  const int tid = threadIdx.x;
  const int wave = tid >> 6, lane = tid & 63;
  const int bm = blockIdx.x, bn = blockIdx.y, gz = blockIdx.z;
  const int wm = (wave >> 2) * 128, wn = (wave & 3) * 64;
  const int lrow = lane & 15, lgrp = lane >> 4;

  f32x4 acc[8][4];
#pragma unroll
  for (int m = 0; m < 8; ++m)
#pragma unroll
    for (int n = 0; n < 4; ++n) acc[m][n] = (f32x4){0.f, 0.f, 0.f, 0.f};

  gemm256_core(ga.A[gz], ga.W[gz], lds, tid, wave, lane, bm, bn, acc);

  const float* bias = ga.bias[gz];
  unsigned short* out = ga.out[gz];
  float bv[4];
#pragma unroll
  for (int n = 0; n < 4; ++n) bv[n] = bias[bn * 256 + wn + n * 16 + lrow];

#pragma unroll
  for (int m = 0; m < 8; ++m)
#pragma unroll
    for (int n = 0; n < 4; ++n) {
      const int gc = bn * 256 + wn + n * 16 + lrow;
#pragma unroll
      for (int j = 0; j < 4; ++j) {
        const int gr = bm * 256 + wm + m * 16 + lgrp * 4 + j;
        float v = acc[m][n][j] + bv[n];
        if (gz == 0) v = sigmoidf_(v + 1.0f);       // f gate
        else if (gz == 3) v = tanhf(v);             // tanh(z)
        else v = sigmoidf_(v);                      // o gate, sigmoid(i)
        out[(size_t)gr * GN + gc] = f2bf(v);
      }
    }
}

// ---------------- output projection: 256x128 tile, 256 blocks (full machine) ----------------
__global__ __launch_bounds__(512, 2) void gemm_proj_bn128(
    const unsigned short* __restrict__ A, const unsigned short* __restrict__ W,
    const float* __restrict__ bias, float* __restrict__ out) {
  extern __shared__ char lds[];  // A: 2 x 32K at 0; B: 2 x 16K at 65536
  const int tid = threadIdx.x;
  const int wave = tid >> 6, lane = tid & 63;
  const int bm = blockIdx.x, bn = blockIdx.y;
  const int wm = (wave >> 2) * 128, wn = (wave & 3) * 32;
  const int lrow = lane & 15, lgrp = lane >> 4;

  f32x4 acc[8][2];
#pragma unroll
  for (int m = 0; m < 8; ++m)
#pragma unroll
    for (int n = 0; n < 2; ++n) acc[m][n] = (f32x4){0.f, 0.f, 0.f, 0.f};

  const char* gsrc[6];
  char* ldst[6];
  {
    const char* Ag = (const char*)A;
    const char* Wg = (const char*)W;
#pragma unroll
    for (int i = 0; i < 4; ++i) {  // A: 4 loads/thread, rows 0..255
      const int lbyte = i * 8192 + tid * 16;
      const int row = lbyte >> 7;
      const int gcb = (lbyte & 127) ^ ((row & 7) << 4);
      gsrc[i] = Ag + (size_t)(bm * 256 + row) * 2048 + gcb;
      ldst[i] = lds + i * 8192 + wave * 1024;
    }
#pragma unroll
    for (int j = 0; j < 2; ++j) {  // B: 2 loads/thread, rows 0..127
      const int lbyte = j * 8192 + tid * 16;
      const int row = lbyte >> 7;
      const int gcb = (lbyte & 127) ^ ((row & 7) << 4);
      gsrc[4 + j] = Wg + (size_t)(bn * 128 + row) * 2048 + gcb;
      ldst[4 + j] = lds + 65536 + j * 8192 + wave * 1024;
    }
  }

  // prologue: tile 0 (A4 + B2)
#pragma unroll
  for (int i = 0; i < 6; ++i) gload16(gsrc[i], ldst[i]);

  bf16x8 aLo[4][2], aHi[4][2], bF[2][2];

  for (int t = 0; t < NT; ++t) {
    const int cur = t & 1;
    const int obufA = (cur ^ 1) * 32768;
    const int obufB = (cur ^ 1) * 16384;
    const char* Abase = lds + cur * 32768;
    const char* Bbase = lds + 65536 + cur * 16384;
    const int nk = (t + 1 < NT) ? (t + 1) : (NT - 1);
    const size_t koff = (size_t)nk * 128;

    // ---- P1: stage A(t+1); vmcnt(4); bar; reads aLo+bF; MFMA q1 ----
#pragma unroll
    for (int i = 0; i < 4; ++i) gload16(gsrc[i] + koff, ldst[i] + obufA);
    asm volatile("s_waitcnt vmcnt(4)" ::: "memory");
    __builtin_amdgcn_s_barrier();
    SB();
#pragma unroll
    for (int m = 0; m < 4; ++m)
#pragma unroll
      for (int ks = 0; ks < 2; ++ks) {
        const int r = wm + m * 16 + lrow;
        const int cb = ks * 64 + lgrp * 16;
        aLo[m][ks] = *(const bf16x8*)(Abase + r * 128 + (cb ^ ((r & 7) << 4)));
      }
#pragma unroll
    for (int n = 0; n < 2; ++n)
#pragma unroll
      for (int ks = 0; ks < 2; ++ks) {
        const int nr = wn + n * 16 + lrow;
        const int cb = ks * 64 + lgrp * 16;
        bF[n][ks] = *(const bf16x8*)(Bbase + nr * 128 + (cb ^ ((nr & 7) << 4)));
      }
    __builtin_amdgcn_s_setprio(1);
#pragma unroll
    for (int m = 0; m < 4; ++m)
#pragma unroll
      for (int n = 0; n < 2; ++n)
#pragma unroll
        for (int ks = 0; ks < 2; ++ks)
          acc[m][n] = __builtin_amdgcn_mfma_f32_16x16x32_bf16(aLo[m][ks], bF[n][ks],
                                                              acc[m][n], 0, 0, 0);
    __builtin_amdgcn_s_setprio(0);

    // ---- P2: reads aHi; stage B(t+1); bar; lgkm0; MFMA q2 ----
#pragma unroll
    for (int m = 0; m < 4; ++m)
#pragma unroll
      for (int ks = 0; ks < 2; ++ks) {
        const int r = wm + (m + 4) * 16 + lrow;
        const int cb = ks * 64 + lgrp * 16;
        aHi[m][ks] = *(const bf16x8*)(Abase + r * 128 + (cb ^ ((r & 7) << 4)));
      }
#pragma unroll
    for (int j = 4; j < 6; ++j) gload16(gsrc[j] + koff, ldst[j] + obufB);
    __builtin_amdgcn_s_barrier();
    asm volatile("s_waitcnt lgkmcnt(0)" ::: "memory");
    SB();
    __builtin_amdgcn_s_setprio(1);
#pragma unroll
    for (int m = 0; m < 4; ++m)
#pragma unroll
      for (int n = 0; n < 2; ++n)
#pragma unroll
        for (int ks = 0; ks < 2; ++ks)
          acc[m + 4][n] = __builtin_amdgcn_mfma_f32_16x16x32_bf16(aHi[m][ks], bF[n][ks],
                                                                  acc[m + 4][n], 0, 0, 0);
    __builtin_amdgcn_s_setprio(0);
  }

  float bv[2];
#pragma unroll
  for (int n = 0; n < 2; ++n) bv[n] = bias[bn * 128 + wn + n * 16 + lrow];

#pragma unroll
  for (int m = 0; m < 8; ++m)
#pragma unroll
    for (int n = 0; n < 2; ++n) {
      const int gc = bn * 128 + wn + n * 16 + lrow;
#pragma unroll
      for (int j = 0; j < 4; ++j) {
        const int gr = bm * 256 + wm + m * 16 + lgrp * 4 + j;
        out[(size_t)gr * GN + gc] = acc[m][n][j] + bv[n];
      }
    }
}

// ---------------- scan phase A: per-chunk (prod f, local c); u = si*tz ----------------
__global__ void scan_phaseA_kernel(const unsigned short* __restrict__ F,
                                   const unsigned short* __restrict__ Si,
                                   const unsigned short* __restrict__ Tz,
                                   float* __restrict__ Pt, float* __restrict__ Ct) {
  int tid = blockIdx.x * blockDim.x + threadIdx.x;  // NCH * NCHUNK = 262144
  int ch = tid & (NCH - 1), chunk = tid >> 12;
  int b = ch >> 10, n = ch & 1023;
  size_t base = ((size_t)(b * 2048 + chunk * CHUNK)) * 1024 + n;
  float c = 0.f, P = 1.f;
#pragma unroll 8
  for (int t = 0; t < CHUNK; ++t) {
    size_t idx = base + (size_t)t * 1024;
    float f = bf2f(F[idx]);
    float u = bf2f(Si[idx]) * bf2f(Tz[idx]);
    c = __builtin_fmaf(f, c, u);
    P *= f;
  }
  Pt[tid] = P;
  Ct[tid] = c;
}

// ---------------- scan combine: sequential over 64 chunks ----------------
__global__ void scan_combine_kernel(const float* __restrict__ Pt,
                                    const float* __restrict__ Ct,
                                    const float* __restrict__ c0,
                                    float* __restrict__ Cin,
                                    float* __restrict__ last_c) {
  int ch = blockIdx.x * blockDim.x + threadIdx.x;  // 4096
  float c = c0[ch];
#pragma unroll
  for (int j = 0; j < NCHUNK; ++j) {
    Cin[j * NCH + ch] = c;
    c = __builtin_fmaf(Pt[j * NCH + ch], c, Ct[j * NCH + ch]);
  }
  last_c[ch] = c;
}

// ---------------- scan phase C: replay with carry, emit h ----------------
__global__ void scan_phaseC_kernel(const unsigned short* __restrict__ F,
                                   const unsigned short* __restrict__ Si,
                                   const unsigned short* __restrict__ Tz,
                                   const unsigned short* __restrict__ O,
                                   const float* __restrict__ Cin,
                                   unsigned short* __restrict__ Hb,
                                   float* __restrict__ last_h) {
  int tid = blockIdx.x * blockDim.x + threadIdx.x;
  int ch = tid & (NCH - 1), chunk = tid >> 12;
  int b = ch >> 10, n = ch & 1023;
  size_t base = ((size_t)(b * 2048 + chunk * CHUNK)) * 1024 + n;
  float c = Cin[tid];  // tid == chunk*NCH + ch
  float h = 0.f;
#pragma unroll 8
  for (int t = 0; t < CHUNK; ++t) {
    size_t idx = base + (size_t)t * 1024;
    float f = bf2f(F[idx]);
    float u = bf2f(Si[idx]) * bf2f(Tz[idx]);
    float o = bf2f(O[idx]);
    c = __builtin_fmaf(f, c, u);
    h = o * tanhf(c);
    Hb[idx] = f2bf(h);
  }
  if (chunk == NCHUNK - 1) last_h[ch] = h;
}

extern "C" void kernel_launch(void* const* d_in, const int* in_sizes, int n_in,
                              void* d_out, int out_size, void* d_ws, size_t ws_size,
                              hipStream_t stream) {
  const float* f_in = (const float*)d_in[0];
  const float* i_in = (const float*)d_in[1];
  const float* z_in = (const float*)d_in[2];
  const float* o_in = (const float*)d_in[3];
  const float* c0 = (const float*)d_in[4];
  // d_in[5] = h0 (unused by reference)
  const float* Wf = (const float*)d_in[6];
  const float* bf_ = (const float*)d_in[7];
  const float* Wi = (const float*)d_in[8];
  const float* bi = (const float*)d_in[9];
  const float* Wz = (const float*)d_in[10];
  const float* bz = (const float*)d_in[11];
  const float* Wo = (const float*)d_in[12];
  const float* bo = (const float*)d_in[13];
  const float* Wp = (const float*)d_in[14];
  const float* bp = (const float*)d_in[15];

  float* y = (float*)d_out;
  float* last_c = y + NACT;
  float* last_h = last_c + NCH;

  // workspace carve (Hb aliases Af; both dead/live regions disjoint in time)
  char* w = (char*)d_ws;
  const size_t ABYTES = NACT * 2;             // 16 MiB
  const size_t WBYTES = (size_t)GK * GN * 2;  // 2 MiB
  unsigned short* Af = (unsigned short*)(w + 0 * ABYTES);
  unsigned short* Ai = (unsigned short*)(w + 1 * ABYTES);
  unsigned short* Az = (unsigned short*)(w + 2 * ABYTES);
  unsigned short* Ao = (unsigned short*)(w + 3 * ABYTES);
  char* wt = w + 4 * ABYTES;
  unsigned short* Wtf = (unsigned short*)(wt + 0 * WBYTES);
  unsigned short* Wti = (unsigned short*)(wt + 1 * WBYTES);
  unsigned short* Wtz = (unsigned short*)(wt + 2 * WBYTES);
  unsigned short* Wto = (unsigned short*)(wt + 3 * WBYTES);
  unsigned short* Wtp = (unsigned short*)(wt + 4 * WBYTES);
  char* gp = wt + 5 * WBYTES;
  unsigned short* F = (unsigned short*)(gp + 0 * ABYTES);
  unsigned short* O = (unsigned short*)(gp + 1 * ABYTES);
  unsigned short* Si = (unsigned short*)(gp + 2 * ABYTES);  // sigmoid(i+bi)
  unsigned short* Tz = (unsigned short*)(gp + 3 * ABYTES);  // tanh(z+bz)
  unsigned short* Hb = Af;  // alias: Af dead after gate GEMMs
  char* sp = gp + 4 * ABYTES;
  const size_t SBYTES = (size_t)NCH * NCHUNK * 4;  // 1 MiB
  float* Pt = (float*)(sp + 0 * SBYTES);
  float* Ct = (float*)(sp + 1 * SBYTES);
  float* Cin = (float*)(sp + 2 * SBYTES);

  // allow dynamic LDS (idempotent, capture-safe)
  (void)hipFuncSetAttribute((const void*)gemm_gates8,
                            hipFuncAttributeMaxDynamicSharedMemorySize, 131072);
  (void)hipFuncSetAttribute((const void*)gemm_proj_bn128,
                            hipFuncAttributeMaxDynamicSharedMemorySize, 98304);

  // 1) prep: convert activations + transpose weights (one dispatch)
  PrepArgs pa;
  pa.csrc[0] = f_in; pa.csrc[1] = o_in; pa.csrc[2] = i_in; pa.csrc[3] = z_in;
  pa.cdst[0] = Af;   pa.cdst[1] = Ao;   pa.cdst[2] = Ai;   pa.cdst[3] = Az;
  pa.tsrc[0] = Wf; pa.tsrc[1] = Wi; pa.tsrc[2] = Wz; pa.tsrc[3] = Wo; pa.tsrc[4] = Wp;
  pa.tdst[0] = Wtf; pa.tdst[1] = Wti; pa.tdst[2] = Wtz; pa.tdst[3] = Wto; pa.tdst[4] = Wtp;
  prep_kernel<<<9216, 256, 0, stream>>>(pa);

  // 2) all 4 gate GEMMs in one dispatch (512 blocks = 2 full CU rounds)
  GateArgs ga;
  ga.A[0] = Af;  ga.A[1] = Ao;  ga.A[2] = Ai;  ga.A[3] = Az;
  ga.W[0] = Wtf; ga.W[1] = Wto; ga.W[2] = Wti; ga.W[3] = Wtz;
  ga.bias[0] = bf_; ga.bias[1] = bo; ga.bias[2] = bi; ga.bias[3] = bz;
  ga.out[0] = F; ga.out[1] = O; ga.out[2] = Si; ga.out[3] = Tz;
  gemm_gates8<<<dim3(GM / 256, GN / 256, 4), 512, 131072, stream>>>(ga);

  // 3) chunked linear-recurrence scan (u = Si*Tz, one multiply)
  scan_phaseA_kernel<<<(NCH * NCHUNK) / 256, 256, 0, stream>>>(F, Si, Tz, Pt, Ct);
  scan_combine_kernel<<<NCH / 256, 256, 0, stream>>>(Pt, Ct, c0, Cin, last_c);
  scan_phaseC_kernel<<<(NCH * NCHUNK) / 256, 256, 0, stream>>>(F, Si, Tz, O, Cin, Hb,
                                                               last_h);

  // 4) output projection: 256x128 tiles, 256 blocks = full machine
  gemm_proj_bn128<<<dim3(GM / 256, GN / 128), 512, 98304, stream>>>(Hb, Wtp, bp, y);
}

// Round 9
// 199.409 us; speedup vs baseline: 1.0712x; 1.0712x over previous
//
#include <hip/hip_runtime.h>
#include <hip/hip_bf16.h>
#include <stdint.h>

// B=4, S=2048, HDIM=1024, H=16, D=64, L=128, NB=16
// GEMMs: M = B*S = 8192, N = H*D = 1024, K = HDIM = 1024
constexpr int GM = 8192;
constexpr int GK = 1024;
constexpr int GN = 1024;
constexpr size_t NACT = (size_t)GM * GN;      // 8388608 elements
constexpr int CHUNK = 32;                      // scan chunk length
constexpr int NCHUNK = 64;                     // 64*32 = 2048 = S
constexpr int NCH = 4096;                      // B*H*D channels
constexpr int NT = GK / 64;                    // 16 K-tiles of 64

#define DEVINL __device__ __forceinline__

typedef __attribute__((ext_vector_type(8))) short bf16x8;
typedef __attribute__((ext_vector_type(4))) float f32x4;

DEVINL float sigmoidf_(float x) { return 1.0f / (1.0f + __expf(-x)); }

DEVINL unsigned short f2bf(float x) {
  unsigned int u = __builtin_bit_cast(unsigned int, x);
  unsigned int rnd = 0x7fffu + ((u >> 16) & 1u);
  return (unsigned short)((u + rnd) >> 16);
}
DEVINL float bf2f(unsigned short u) {
  unsigned int x = ((unsigned int)u) << 16;
  return __builtin_bit_cast(float, x);
}

DEVINL void gload16(const void* g, void* l) {
  __builtin_amdgcn_global_load_lds(
      (const __attribute__((address_space(1))) unsigned int*)g,
      (__attribute__((address_space(3))) unsigned int*)l, 16, 0, 0);
}

#define SB() __builtin_amdgcn_sched_barrier(0)

// ---------------- prep: cvt 4 activations + transpose 5 weights, ONE dispatch ----------------
struct PrepArgs {
  const float* csrc[4];
  unsigned short* cdst[4];
  const float* tsrc[5];
  unsigned short* tdst[5];
};

__global__ __launch_bounds__(256) void prep_kernel(PrepArgs p) {
  const int bx = blockIdx.x;
  if (bx < 4096) {
    // cvt part: 1024 blocks per array, 8 float4 per thread
    const float* s = p.csrc[bx >> 10];
    unsigned short* d = p.cdst[bx >> 10];
    int i = (bx & 1023) * 256 + threadIdx.x;
    const int stride = 1024 * 256;
#pragma unroll
    for (int it = 0; it < 8; ++it, i += stride) {
      float4 v = ((const float4*)s)[i];
      ushort4 o;
      o.x = f2bf(v.x); o.y = f2bf(v.y); o.z = f2bf(v.z); o.w = f2bf(v.w);
      ((ushort4*)d)[i] = o;
    }
  } else {
    // transpose part: 1024 blocks per weight (32x32 tiles over 1024^2)
    const int t = bx - 4096;
    const float* __restrict__ W = p.tsrc[t >> 10];
    unsigned short* __restrict__ Wt = p.tdst[t >> 10];
    const int rem = t & 1023;
    const int n0 = (rem & 31) * 32, k0 = (rem >> 5) * 32;
    __shared__ float tile[32][33];
    int tx = threadIdx.x & 31, ty = threadIdx.x >> 5;  // 32x8
#pragma unroll
    for (int i = 0; i < 32; i += 8)
      tile[ty + i][tx] = W[(size_t)(k0 + ty + i) * GN + n0 + tx];
    __syncthreads();
#pragma unroll
    for (int i = 0; i < 32; i += 8)
      Wt[(size_t)(n0 + ty + i) * GK + k0 + tx] = f2bf(tile[tx][ty + i]);
  }
}

// =====================================================================
// 256x256 tile, BK=64, 8 waves (2M x 4N) -- round-4 schedule (best: 86.4us).
//  P1: stage A(t+1); vmcnt(4); barrier; read q1; MFMA (mlo,nlo)
//  P2: read bF-hi; stage B(t+1); barrier; lgkm0; MFMA (mlo,nhi)
//  P3: read aF-hi; barrier; lgkm0; MFMA (mhi,nhi)
//  P4: MFMA (mhi,nlo) -- no loads/barrier; overlaps next P1 stage
// LDS 128 KiB: 2 dbuf x (A 32K + B 32K), linear dest + inverse-XOR-swizzled
// global source; reads apply the same XOR involution: cb ^= (row&7)<<4.
// =====================================================================
DEVINL void gemm256_core(const unsigned short* __restrict__ A,
                         const unsigned short* __restrict__ W,
                         char* lds, int tid, int wave, int lane,
                         int bm, int bn, f32x4 (&acc)[8][4]) {
  const int Ah = wave >> 2;
  const int wn = (wave & 3) * 64;
  const int lrow = lane & 15;
  const int lgrp = lane >> 4;

  const char* gsrc[8];
  char* ldst[8];
  {
    const char* Ag = (const char*)A;
    const char* Wg = (const char*)W;
#pragma unroll
    for (int hh = 0; hh < 4; ++hh)
#pragma unroll
      for (int j = 0; j < 2; ++j) {
        const int lbyte = j * 8192 + tid * 16;
        const int row = lbyte >> 7;
        const int gcb = (lbyte & 127) ^ ((row & 7) << 4);
        const int i = hh * 2 + j;
        gsrc[i] = (hh < 2)
            ? Ag + (size_t)(bm * 256 + hh * 128 + row) * 2048 + gcb
            : Wg + (size_t)(bn * 256 + (hh - 2) * 128 + row) * 2048 + gcb;
        ldst[i] = lds + (hh >= 2 ? 32768 : 0) + (hh & 1) * 16384 + j * 8192 +
                  wave * 1024;
      }
  }

#pragma unroll
  for (int i = 0; i < 8; ++i) gload16(gsrc[i], ldst[i]);

  bf16x8 aF[4][2], bF[4][2];

  for (int t = 0; t < NT; ++t) {
    const int cur = t & 1;
    const int obuf = (cur ^ 1) * 65536;
    const char* Abase = lds + cur * 65536 + Ah * 16384;
    const char* Bbase = lds + cur * 65536 + 32768;
    const int nk = (t + 1 < NT) ? (t + 1) : (NT - 1);
    const size_t koff = (size_t)nk * 128;

    // ---- P1 ----
#pragma unroll
    for (int i = 0; i < 4; ++i) gload16(gsrc[i] + koff, ldst[i] + obuf);
    asm volatile("s_waitcnt vmcnt(4)" ::: "memory");
    __builtin_amdgcn_s_barrier();
    SB();
#pragma unroll
    for (int m = 0; m < 4; ++m)
#pragma unroll
      for (int ks = 0; ks < 2; ++ks) {
        const int r = m * 16 + lrow;
        const int cb = ks * 64 + lgrp * 16;
        aF[m][ks] = *(const bf16x8*)(Abase + r * 128 + (cb ^ ((r & 7) << 4)));
      }
#pragma unroll
    for (int n = 0; n < 2; ++n)
#pragma unroll
      for (int ks = 0; ks < 2; ++ks) {
        const int nr = wn + n * 16 + lrow;
        const int cb = ks * 64 + lgrp * 16;
        bF[n][ks] = *(const bf16x8*)(Bbase + nr * 128 + (cb ^ ((nr & 7) << 4)));
      }
    __builtin_amdgcn_s_setprio(1);
#pragma unroll
    for (int m = 0; m < 4; ++m)
#pragma unroll
      for (int n = 0; n < 2; ++n)
#pragma unroll
        for (int ks = 0; ks < 2; ++ks)
          acc[m][n] = __builtin_amdgcn_mfma_f32_16x16x32_bf16(aF[m][ks], bF[n][ks],
                                                              acc[m][n], 0, 0, 0);
    __builtin_amdgcn_s_setprio(0);

    // ---- P2 ----
#pragma unroll
    for (int n = 2; n < 4; ++n)
#pragma unroll
      for (int ks = 0; ks < 2; ++ks) {
        const int nr = wn + n * 16 + lrow;
        const int cb = ks * 64 + lgrp * 16;
        bF[n][ks] = *(const bf16x8*)(Bbase + nr * 128 + (cb ^ ((nr & 7) << 4)));
      }
#pragma unroll
    for (int i = 4; i < 8; ++i) gload16(gsrc[i] + koff, ldst[i] + obuf);
    __builtin_amdgcn_s_barrier();
    asm volatile("s_waitcnt lgkmcnt(0)" ::: "memory");
    SB();
    __builtin_amdgcn_s_setprio(1);
#pragma unroll
    for (int m = 0; m < 4; ++m)
#pragma unroll
      for (int n = 2; n < 4; ++n)
#pragma unroll
        for (int ks = 0; ks < 2; ++ks)
          acc[m][n] = __builtin_amdgcn_mfma_f32_16x16x32_bf16(aF[m][ks], bF[n][ks],
                                                              acc[m][n], 0, 0, 0);
    __builtin_amdgcn_s_setprio(0);

    // ---- P3 ----
#pragma unroll
    for (int m = 0; m < 4; ++m)
#pragma unroll
      for (int ks = 0; ks < 2; ++ks) {
        const int r = (m + 4) * 16 + lrow;
        const int cb = ks * 64 + lgrp * 16;
        aF[m][ks] = *(const bf16x8*)(Abase + r * 128 + (cb ^ ((r & 7) << 4)));
      }
    __builtin_amdgcn_s_barrier();
    asm volatile("s_waitcnt lgkmcnt(0)" ::: "memory");
    SB();
    __builtin_amdgcn_s_setprio(1);
#pragma unroll
    for (int m = 0; m < 4; ++m)
#pragma unroll
      for (int n = 2; n < 4; ++n)
#pragma unroll
        for (int ks = 0; ks < 2; ++ks)
          acc[m + 4][n] = __builtin_amdgcn_mfma_f32_16x16x32_bf16(aF[m][ks], bF[n][ks],
                                                                  acc[m + 4][n], 0, 0, 0);
    __builtin_amdgcn_s_setprio(0);

    // ---- P4 ----
    __builtin_amdgcn_s_setprio(1);
#pragma unroll
    for (int m = 0; m < 4; ++m)
#pragma unroll
      for (int n = 0; n < 2; ++n)
#pragma unroll
        for (int ks = 0; ks < 2; ++ks)
          acc[m + 4][n] = __builtin_amdgcn_mfma_f32_16x16x32_bf16(aF[m][ks], bF[n][ks],
                                                                  acc[m + 4][n], 0, 0, 0);
    __builtin_amdgcn_s_setprio(0);
  }
}

// ---------------- batched gate GEMM: z = {f, o, i_raw, z_raw} (round-4 epilogue) ----------------
struct GateArgs {
  const unsigned short* A[4];
  const unsigned short* W[4];
  const float* bias[4];
  unsigned short* out[4];
};

__global__ __launch_bounds__(512, 2) void gemm_gates8(GateArgs ga) {
  extern __shared__ char lds[];
  const int tid = threadIdx.x;
  const int wave = tid >> 6, lane = tid & 63;
  const int bm = blockIdx.x, bn = blockIdx.y, gz = blockIdx.z;
  const int wm = (wave >> 2) * 128, wn = (wave & 3) * 64;
  const int lrow = lane & 15, lgrp = lane >> 4;

  f32x4 acc[8][4];
#pragma unroll
  for (int m = 0; m < 8; ++m)
#pragma unroll
    for (int n = 0; n < 4; ++n) acc[m][n] = (f32x4){0.f, 0.f, 0.f, 0.f};

  gemm256_core(ga.A[gz], ga.W[gz], lds, tid, wave, lane, bm, bn, acc);

  const float* bias = ga.bias[gz];
  unsigned short* out = ga.out[gz];
  float bv[4];
#pragma unroll
  for (int n = 0; n < 4; ++n) bv[n] = bias[bn * 256 + wn + n * 16 + lrow];

#pragma unroll
  for (int m = 0; m < 8; ++m)
#pragma unroll
    for (int n = 0; n < 4; ++n) {
      const int gc = bn * 256 + wn + n * 16 + lrow;
#pragma unroll
      for (int j = 0; j < 4; ++j) {
        const int gr = bm * 256 + wm + m * 16 + lgrp * 4 + j;
        float v = acc[m][n][j] + bv[n];
        if (gz == 0) v = sigmoidf_(v + 1.0f);       // f gate
        else if (gz == 1) v = sigmoidf_(v);         // o gate
        // gz==2 (i) / gz==3 (z): raw pre-activation (bias included)
        out[(size_t)gr * GN + gc] = f2bf(v);
      }
    }
}

// ---------------- output projection: 256x128 tile, 256 blocks (full machine) ----------------
__global__ __launch_bounds__(512, 2) void gemm_proj_bn128(
    const unsigned short* __restrict__ A, const unsigned short* __restrict__ W,
    const float* __restrict__ bias, float* __restrict__ out) {
  extern __shared__ char lds[];  // A: 2 x 32K at 0; B: 2 x 16K at 65536
  const int tid = threadIdx.x;
  const int wave = tid >> 6, lane = tid & 63;
  const int bm = blockIdx.x, bn = blockIdx.y;
  const int wm = (wave >> 2) * 128, wn = (wave & 3) * 32;
  const int lrow = lane & 15, lgrp = lane >> 4;

  f32x4 acc[8][2];
#pragma unroll
  for (int m = 0; m < 8; ++m)
#pragma unroll
    for (int n = 0; n < 2; ++n) acc[m][n] = (f32x4){0.f, 0.f, 0.f, 0.f};

  const char* gsrc[6];
  char* ldst[6];
  {
    const char* Ag = (const char*)A;
    const char* Wg = (const char*)W;
#pragma unroll
    for (int i = 0; i < 4; ++i) {  // A: 4 loads/thread, rows 0..255
      const int lbyte = i * 8192 + tid * 16;
      const int row = lbyte >> 7;
      const int gcb = (lbyte & 127) ^ ((row & 7) << 4);
      gsrc[i] = Ag + (size_t)(bm * 256 + row) * 2048 + gcb;
      ldst[i] = lds + i * 8192 + wave * 1024;
    }
#pragma unroll
    for (int j = 0; j < 2; ++j) {  // B: 2 loads/thread, rows 0..127
      const int lbyte = j * 8192 + tid * 16;
      const int row = lbyte >> 7;
      const int gcb = (lbyte & 127) ^ ((row & 7) << 4);
      gsrc[4 + j] = Wg + (size_t)(bn * 128 + row) * 2048 + gcb;
      ldst[4 + j] = lds + 65536 + j * 8192 + wave * 1024;
    }
  }

  // prologue: tile 0 (A4 + B2)
#pragma unroll
  for (int i = 0; i < 6; ++i) gload16(gsrc[i], ldst[i]);

  bf16x8 aLo[4][2], aHi[4][2], bF[2][2];

  for (int t = 0; t < NT; ++t) {
    const int cur = t & 1;
    const int obufA = (cur ^ 1) * 32768;
    const int obufB = (cur ^ 1) * 16384;
    const char* Abase = lds + cur * 32768;
    const char* Bbase = lds + 65536 + cur * 16384;
    const int nk = (t + 1 < NT) ? (t + 1) : (NT - 1);
    const size_t koff = (size_t)nk * 128;

    // ---- P1: stage A(t+1); vmcnt(4); bar; reads aLo+bF; MFMA q1 ----
#pragma unroll
    for (int i = 0; i < 4; ++i) gload16(gsrc[i] + koff, ldst[i] + obufA);
    asm volatile("s_waitcnt vmcnt(4)" ::: "memory");
    __builtin_amdgcn_s_barrier();
    SB();
#pragma unroll
    for (int m = 0; m < 4; ++m)
#pragma unroll
      for (int ks = 0; ks < 2; ++ks) {
        const int r = wm + m * 16 + lrow;
        const int cb = ks * 64 + lgrp * 16;
        aLo[m][ks] = *(const bf16x8*)(Abase + r * 128 + (cb ^ ((r & 7) << 4)));
      }
#pragma unroll
    for (int n = 0; n < 2; ++n)
#pragma unroll
      for (int ks = 0; ks < 2; ++ks) {
        const int nr = wn + n * 16 + lrow;
        const int cb = ks * 64 + lgrp * 16;
        bF[n][ks] = *(const bf16x8*)(Bbase + nr * 128 + (cb ^ ((nr & 7) << 4)));
      }
    __builtin_amdgcn_s_setprio(1);
#pragma unroll
    for (int m = 0; m < 4; ++m)
#pragma unroll
      for (int n = 0; n < 2; ++n)
#pragma unroll
        for (int ks = 0; ks < 2; ++ks)
          acc[m][n] = __builtin_amdgcn_mfma_f32_16x16x32_bf16(aLo[m][ks], bF[n][ks],
                                                              acc[m][n], 0, 0, 0);
    __builtin_amdgcn_s_setprio(0);

    // ---- P2: reads aHi; stage B(t+1); bar; lgkm0; MFMA q2 ----
#pragma unroll
    for (int m = 0; m < 4; ++m)
#pragma unroll
      for (int ks = 0; ks < 2; ++ks) {
        const int r = wm + (m + 4) * 16 + lrow;
        const int cb = ks * 64 + lgrp * 16;
        aHi[m][ks] = *(const bf16x8*)(Abase + r * 128 + (cb ^ ((r & 7) << 4)));
      }
#pragma unroll
    for (int j = 4; j < 6; ++j) gload16(gsrc[j] + koff, ldst[j] + obufB);
    __builtin_amdgcn_s_barrier();
    asm volatile("s_waitcnt lgkmcnt(0)" ::: "memory");
    SB();
    __builtin_amdgcn_s_setprio(1);
#pragma unroll
    for (int m = 0; m < 4; ++m)
#pragma unroll
      for (int n = 0; n < 2; ++n)
#pragma unroll
        for (int ks = 0; ks < 2; ++ks)
          acc[m + 4][n] = __builtin_amdgcn_mfma_f32_16x16x32_bf16(aHi[m][ks], bF[n][ks],
                                                                  acc[m + 4][n], 0, 0, 0);
    __builtin_amdgcn_s_setprio(0);
  }

  float bv[2];
#pragma unroll
  for (int n = 0; n < 2; ++n) bv[n] = bias[bn * 128 + wn + n * 16 + lrow];

#pragma unroll
  for (int m = 0; m < 8; ++m)
#pragma unroll
    for (int n = 0; n < 2; ++n) {
      const int gc = bn * 128 + wn + n * 16 + lrow;
#pragma unroll
      for (int j = 0; j < 4; ++j) {
        const int gr = bm * 256 + wm + m * 16 + lgrp * 4 + j;
        out[(size_t)gr * GN + gc] = acc[m][n][j] + bv[n];
      }
    }
}

// ---------------- scan phase A: per-chunk (prod f, local c) ----------------
__global__ void scan_phaseA_kernel(const unsigned short* __restrict__ F,
                                   const unsigned short* __restrict__ Ip,
                                   const unsigned short* __restrict__ Zp,
                                   float* __restrict__ Pt, float* __restrict__ Ct) {
  int tid = blockIdx.x * blockDim.x + threadIdx.x;  // NCH * NCHUNK = 262144
  int ch = tid & (NCH - 1), chunk = tid >> 12;
  int b = ch >> 10, n = ch & 1023;
  size_t base = ((size_t)(b * 2048 + chunk * CHUNK)) * 1024 + n;
  float c = 0.f, P = 1.f;
#pragma unroll 8
  for (int t = 0; t < CHUNK; ++t) {
    size_t idx = base + (size_t)t * 1024;
    float f = bf2f(F[idx]);
    float u = sigmoidf_(bf2f(Ip[idx])) * tanhf(bf2f(Zp[idx]));
    c = __builtin_fmaf(f, c, u);
    P *= f;
  }
  Pt[tid] = P;
  Ct[tid] = c;
}

// ---------------- scan combine: sequential over 64 chunks ----------------
__global__ void scan_combine_kernel(const float* __restrict__ Pt,
                                    const float* __restrict__ Ct,
                                    const float* __restrict__ c0,
                                    float* __restrict__ Cin,
                                    float* __restrict__ last_c) {
  int ch = blockIdx.x * blockDim.x + threadIdx.x;  // 4096
  float c = c0[ch];
#pragma unroll
  for (int j = 0; j < NCHUNK; ++j) {
    Cin[j * NCH + ch] = c;
    c = __builtin_fmaf(Pt[j * NCH + ch], c, Ct[j * NCH + ch]);
  }
  last_c[ch] = c;
}

// ---------------- scan phase C: replay with carry, emit h ----------------
__global__ void scan_phaseC_kernel(const unsigned short* __restrict__ F,
                                   const unsigned short* __restrict__ Ip,
                                   const unsigned short* __restrict__ Zp,
                                   const unsigned short* __restrict__ O,
                                   const float* __restrict__ Cin,
                                   unsigned short* __restrict__ Hb,
                                   float* __restrict__ last_h) {
  int tid = blockIdx.x * blockDim.x + threadIdx.x;
  int ch = tid & (NCH - 1), chunk = tid >> 12;
  int b = ch >> 10, n = ch & 1023;
  size_t base = ((size_t)(b * 2048 + chunk * CHUNK)) * 1024 + n;
  float c = Cin[tid];  // tid == chunk*NCH + ch
  float h = 0.f;
#pragma unroll 8
  for (int t = 0; t < CHUNK; ++t) {
    size_t idx = base + (size_t)t * 1024;
    float f = bf2f(F[idx]);
    float u = sigmoidf_(bf2f(Ip[idx])) * tanhf(bf2f(Zp[idx]));
    float o = bf2f(O[idx]);
    c = __builtin_fmaf(f, c, u);
    h = o * tanhf(c);
    Hb[idx] = f2bf(h);
  }
  if (chunk == NCHUNK - 1) last_h[ch] = h;
}

extern "C" void kernel_launch(void* const* d_in, const int* in_sizes, int n_in,
                              void* d_out, int out_size, void* d_ws, size_t ws_size,
                              hipStream_t stream) {
  const float* f_in = (const float*)d_in[0];
  const float* i_in = (const float*)d_in[1];
  const float* z_in = (const float*)d_in[2];
  const float* o_in = (const float*)d_in[3];
  const float* c0 = (const float*)d_in[4];
  // d_in[5] = h0 (unused by reference)
  const float* Wf = (const float*)d_in[6];
  const float* bf_ = (const float*)d_in[7];
  const float* Wi = (const float*)d_in[8];
  const float* bi = (const float*)d_in[9];
  const float* Wz = (const float*)d_in[10];
  const float* bz = (const float*)d_in[11];
  const float* Wo = (const float*)d_in[12];
  const float* bo = (const float*)d_in[13];
  const float* Wp = (const float*)d_in[14];
  const float* bp = (const float*)d_in[15];

  float* y = (float*)d_out;
  float* last_c = y + NACT;
  float* last_h = last_c + NCH;

  // workspace carve (Hb aliases Af; disjoint live ranges)
  char* w = (char*)d_ws;
  const size_t ABYTES = NACT * 2;             // 16 MiB
  const size_t WBYTES = (size_t)GK * GN * 2;  // 2 MiB
  unsigned short* Af = (unsigned short*)(w + 0 * ABYTES);
  unsigned short* Ai = (unsigned short*)(w + 1 * ABYTES);
  unsigned short* Az = (unsigned short*)(w + 2 * ABYTES);
  unsigned short* Ao = (unsigned short*)(w + 3 * ABYTES);
  char* wt = w + 4 * ABYTES;
  unsigned short* Wtf = (unsigned short*)(wt + 0 * WBYTES);
  unsigned short* Wti = (unsigned short*)(wt + 1 * WBYTES);
  unsigned short* Wtz = (unsigned short*)(wt + 2 * WBYTES);
  unsigned short* Wto = (unsigned short*)(wt + 3 * WBYTES);
  unsigned short* Wtp = (unsigned short*)(wt + 4 * WBYTES);
  char* gp = wt + 5 * WBYTES;
  unsigned short* F = (unsigned short*)(gp + 0 * ABYTES);
  unsigned short* O = (unsigned short*)(gp + 1 * ABYTES);
  unsigned short* Ip = (unsigned short*)(gp + 2 * ABYTES);
  unsigned short* Zp = (unsigned short*)(gp + 3 * ABYTES);
  unsigned short* Hb = Af;  // alias: Af dead after gate GEMMs
  char* sp = gp + 4 * ABYTES;
  const size_t SBYTES = (size_t)NCH * NCHUNK * 4;  // 1 MiB
  float* Pt = (float*)(sp + 0 * SBYTES);
  float* Ct = (float*)(sp + 1 * SBYTES);
  float* Cin = (float*)(sp + 2 * SBYTES);

  // allow dynamic LDS (idempotent, capture-safe)
  (void)hipFuncSetAttribute((const void*)gemm_gates8,
                            hipFuncAttributeMaxDynamicSharedMemorySize, 131072);
  (void)hipFuncSetAttribute((const void*)gemm_proj_bn128,
                            hipFuncAttributeMaxDynamicSharedMemorySize, 98304);

  // 1) prep: convert activations + transpose weights (one dispatch)
  PrepArgs pa;
  pa.csrc[0] = f_in; pa.csrc[1] = o_in; pa.csrc[2] = i_in; pa.csrc[3] = z_in;
  pa.cdst[0] = Af;   pa.cdst[1] = Ao;   pa.cdst[2] = Ai;   pa.cdst[3] = Az;
  pa.tsrc[0] = Wf; pa.tsrc[1] = Wi; pa.tsrc[2] = Wz; pa.tsrc[3] = Wo; pa.tsrc[4] = Wp;
  pa.tdst[0] = Wtf; pa.tdst[1] = Wti; pa.tdst[2] = Wtz; pa.tdst[3] = Wto; pa.tdst[4] = Wtp;
  prep_kernel<<<9216, 256, 0, stream>>>(pa);

  // 2) all 4 gate GEMMs in one dispatch (512 blocks = 2 full CU rounds)
  GateArgs ga;
  ga.A[0] = Af;  ga.A[1] = Ao;  ga.A[2] = Ai;  ga.A[3] = Az;
  ga.W[0] = Wtf; ga.W[1] = Wto; ga.W[2] = Wti; ga.W[3] = Wtz;
  ga.bias[0] = bf_; ga.bias[1] = bo; ga.bias[2] = bi; ga.bias[3] = bz;
  ga.out[0] = F; ga.out[1] = O; ga.out[2] = Ip; ga.out[3] = Zp;
  gemm_gates8<<<dim3(GM / 256, GN / 256, 4), 512, 131072, stream>>>(ga);

  // 3) chunked linear-recurrence scan (u = sigmoid(ip)*tanh(zp) computed in-scan)
  scan_phaseA_kernel<<<(NCH * NCHUNK) / 256, 256, 0, stream>>>(F, Ip, Zp, Pt, Ct);
  scan_combine_kernel<<<NCH / 256, 256, 0, stream>>>(Pt, Ct, c0, Cin, last_c);
  scan_phaseC_kernel<<<(NCH * NCHUNK) / 256, 256, 0, stream>>>(F, Ip, Zp, O, Cin, Hb,
                                                               last_h);

  // 4) output projection: 256x128 tiles, 256 blocks = full machine
  gemm_proj_bn128<<<dim3(GM / 256, GN / 128), 512, 98304, stream>>>(Hb, Wtp, bp, y);
}